// Round 1
// baseline (208.023 us; speedup 1.0000x reference)
//
#include <hip/hip_runtime.h>
#include <math.h>

// Problem: dual-branch shifted-window self-attention.
// x: (4, 64, 256, 256) f32. Branch 0: channels 0..31, 8x8 windows, no shift.
// Branch 1: channels 32..63, 16x16 windows, shift (8,8).
// Within a branch slice of 32 ch: q = ch 0..15 (head*4+c), v = ch 16..31.
// scores = q @ q^T (no scaling), softmax over s, out = attn @ v.
// out: (4, 32, 256, 256) f32; branch0 -> out ch 0..15, branch1 -> ch 16..31.
//
// Shift (8,8): roll(+8) -> window -> roll(-8) == for rolled coord i' the
// source/dest global coord is (i'-8) mod 256. Read & write the same pixel.

static constexpr int Hh = 256;
static constexpr int Ww = 256;
static constexpr int CIN = 64;
static constexpr int COUT = 32;
static constexpr size_t PLANE = (size_t)Hh * Ww; // 65536

// ---------------- branch 0: 8x8 windows, one wave per (b, head, window) ----
__global__ __launch_bounds__(64) void win8_attn(const float* __restrict__ x,
                                                float* __restrict__ out) {
    int bid = blockIdx.x;
    const int wj   = bid & 31; bid >>= 5;
    const int wi   = bid & 31; bid >>= 5;
    const int head = bid & 3;  bid >>= 2;
    const int b    = bid;

    const int t  = threadIdx.x;        // token 0..63
    const int gi = wi * 8 + (t >> 3);
    const int gj = wj * 8 + (t & 7);
    const size_t pix = (size_t)gi * Ww + gj;

    const float* xq = x + (size_t)b * CIN * PLANE + (size_t)(head * 4) * PLANE + pix;
    const float* xv = xq + 16 * PLANE;

    __shared__ float4 qs[64];
    __shared__ float4 vs[64];

    float4 q, v;
    q.x = xq[0];         q.y = xq[PLANE];     q.z = xq[2 * PLANE]; q.w = xq[3 * PLANE];
    v.x = xv[0];         v.y = xv[PLANE];     v.z = xv[2 * PLANE]; v.w = xv[3 * PLANE];
    qs[t] = q;
    vs[t] = v;
    __syncthreads();

    // scores row in registers (64 VGPRs), single dot pass
    float sc[64];
#pragma unroll
    for (int s = 0; s < 64; ++s) {
        const float4 p = qs[s];                  // LDS broadcast (conflict-free)
        sc[s] = q.x * p.x + q.y * p.y + q.z * p.z + q.w * p.w;
    }
    float m = sc[0];
#pragma unroll
    for (int s = 1; s < 64; ++s) m = fmaxf(m, sc[s]);

    float l = 0.f;
    float4 acc = make_float4(0.f, 0.f, 0.f, 0.f);
#pragma unroll
    for (int s = 0; s < 64; ++s) {
        const float p = __expf(sc[s] - m);
        l += p;
        const float4 vv = vs[s];
        acc.x += p * vv.x; acc.y += p * vv.y;
        acc.z += p * vv.z; acc.w += p * vv.w;
    }
    const float inv = 1.0f / l;

    float* ob = out + (size_t)b * COUT * PLANE + (size_t)(head * 4) * PLANE + pix;
    ob[0]         = acc.x * inv;
    ob[PLANE]     = acc.y * inv;
    ob[2 * PLANE] = acc.z * inv;
    ob[3 * PLANE] = acc.w * inv;
}

// ------- branch 1: 16x16 windows, shift (8,8), 256 threads per window ------
__global__ __launch_bounds__(256) void win16_attn(const float* __restrict__ x,
                                                  float* __restrict__ out) {
    int bid = blockIdx.x;
    const int wj   = bid & 15; bid >>= 4;
    const int wi   = bid & 15; bid >>= 4;
    const int head = bid & 3;  bid >>= 2;
    const int b    = bid;

    const int t  = threadIdx.x;                      // token 0..255
    const int gi = (wi * 16 + (t >> 4) + 248) & 255; // (rolled - 8) mod 256
    const int gj = (wj * 16 + (t & 15) + 248) & 255;
    const size_t pix = (size_t)gi * Ww + gj;

    const float* xq = x + (size_t)b * CIN * PLANE + (size_t)(32 + head * 4) * PLANE + pix;
    const float* xv = xq + 16 * PLANE;

    __shared__ float4 qs[256];
    __shared__ float4 vs[256];

    float4 q, v;
    q.x = xq[0];         q.y = xq[PLANE];     q.z = xq[2 * PLANE]; q.w = xq[3 * PLANE];
    v.x = xv[0];         v.y = xv[PLANE];     v.z = xv[2 * PLANE]; v.w = xv[3 * PLANE];
    qs[t] = q;
    vs[t] = v;
    __syncthreads();

    // pass 1: row max
    float m = -INFINITY;
#pragma unroll 8
    for (int s = 0; s < 256; ++s) {
        const float4 p = qs[s];
        const float d = q.x * p.x + q.y * p.y + q.z * p.z + q.w * p.w;
        m = fmaxf(m, d);
    }

    // pass 2: exp + accumulate PV
    float l = 0.f;
    float4 acc = make_float4(0.f, 0.f, 0.f, 0.f);
#pragma unroll 8
    for (int s = 0; s < 256; ++s) {
        const float4 p = qs[s];
        const float d = q.x * p.x + q.y * p.y + q.z * p.z + q.w * p.w;
        const float e = __expf(d - m);
        l += e;
        const float4 vv = vs[s];
        acc.x += e * vv.x; acc.y += e * vv.y;
        acc.z += e * vv.z; acc.w += e * vv.w;
    }
    const float inv = 1.0f / l;

    float* ob = out + (size_t)b * COUT * PLANE + (size_t)(16 + head * 4) * PLANE + pix;
    ob[0]         = acc.x * inv;
    ob[PLANE]     = acc.y * inv;
    ob[2 * PLANE] = acc.z * inv;
    ob[3 * PLANE] = acc.w * inv;
}

extern "C" void kernel_launch(void* const* d_in, const int* in_sizes, int n_in,
                              void* d_out, int out_size, void* d_ws, size_t ws_size,
                              hipStream_t stream) {
    const float* x = (const float*)d_in[0];
    float* out = (float*)d_out;

    // branch 0: b(4) * head(4) * 32 * 32 windows = 16384 blocks, 64 thr
    hipLaunchKernelGGL(win8_attn, dim3(16384), dim3(64), 0, stream, x, out);
    // branch 1: b(4) * head(4) * 16 * 16 windows = 4096 blocks, 256 thr
    hipLaunchKernelGGL(win16_attn, dim3(4096), dim3(256), 0, stream, x, out);
}

// Round 2
// 98.764 us; speedup vs baseline: 2.1063x; 2.1063x over previous
//
#include <hip/hip_runtime.h>
#include <math.h>

// Dual-branch shifted-window self-attention.
// Branch 0 (ch 0..31 in, ch 0..15 out): 8x8 windows, no shift  -> fp32 vector kernel (only ~4us).
// Branch 1 (ch 32..63 in, ch 16..31 out): 16x16 windows, shift (8,8) -> MFMA kernel.
//
// MFMA formulation (branch 1), per window, per head (dim 4):
//   S = Q @ Q^T  via mfma_f32_16x16x32_bf16 with Dekker split q = q_hi + q_lo:
//       S = hi*hi + lo*hi + hi*lo  (12 of 32 K-slots; K-slot placement is
//       invariant as long as A and B use the same placement).
//   P = exp(S) WITHOUT max subtraction (|S| <= ~40 -> e^S fits fp32/bf16).
//   Unnormalized P is SYMMETRIC, so the QK C-fragment of tile (s,t) is directly
//   the PV A-fragment of tile (t,s): no cross-lane transpose, just exp + cvt.
//   O = P_h@V_h + P_h@V_l + P_l@V_h with a ones-column in V_h producing l = sum_s P.
//   out = O / l.

typedef __attribute__((ext_vector_type(4))) float f32x4;
typedef __attribute__((ext_vector_type(8))) short short8;

static constexpr int Ww = 256;
static constexpr int CIN = 64;
static constexpr int COUT = 32;
static constexpr size_t PLANE = 65536; // 256*256

__device__ inline unsigned short bfhi_u(float x) {
    union { float f; unsigned u; } u; u.f = x;
    return (unsigned short)(u.u >> 16);            // truncation: fine for Dekker split
}
__device__ inline float bf2f(unsigned short h) {
    union { unsigned u; float f; } u; u.u = ((unsigned)h) << 16;
    return u.f;
}

// ---------------- branch 0: 8x8 windows (unchanged, passing, ~4us) ----------
__global__ __launch_bounds__(64) void win8_attn(const float* __restrict__ x,
                                                float* __restrict__ out) {
    int bid = blockIdx.x;
    const int wj   = bid & 31; bid >>= 5;
    const int wi   = bid & 31; bid >>= 5;
    const int head = bid & 3;  bid >>= 2;
    const int b    = bid;

    const int t  = threadIdx.x;
    const int gi = wi * 8 + (t >> 3);
    const int gj = wj * 8 + (t & 7);
    const size_t pix = (size_t)gi * Ww + gj;

    const float* xq = x + (size_t)b * CIN * PLANE + (size_t)(head * 4) * PLANE + pix;
    const float* xv = xq + 16 * PLANE;

    __shared__ float4 qs[64];
    __shared__ float4 vs[64];

    float4 q, v;
    q.x = xq[0];         q.y = xq[PLANE];     q.z = xq[2 * PLANE]; q.w = xq[3 * PLANE];
    v.x = xv[0];         v.y = xv[PLANE];     v.z = xv[2 * PLANE]; v.w = xv[3 * PLANE];
    qs[t] = q;
    vs[t] = v;
    __syncthreads();

    float sc[64];
#pragma unroll
    for (int s = 0; s < 64; ++s) {
        const float4 p = qs[s];
        sc[s] = q.x * p.x + q.y * p.y + q.z * p.z + q.w * p.w;
    }
    float m = sc[0];
#pragma unroll
    for (int s = 1; s < 64; ++s) m = fmaxf(m, sc[s]);

    float l = 0.f;
    float4 acc = make_float4(0.f, 0.f, 0.f, 0.f);
#pragma unroll
    for (int s = 0; s < 64; ++s) {
        const float p = __expf(sc[s] - m);
        l += p;
        const float4 vv = vs[s];
        acc.x += p * vv.x; acc.y += p * vv.y;
        acc.z += p * vv.z; acc.w += p * vv.w;
    }
    const float inv = 1.0f / l;

    float* ob = out + (size_t)b * COUT * PLANE + (size_t)(head * 4) * PLANE + pix;
    ob[0]         = acc.x * inv;
    ob[PLANE]     = acc.y * inv;
    ob[2 * PLANE] = acc.z * inv;
    ob[3 * PLANE] = acc.w * inv;
}

// ---------------- branch 1: 16x16 windows via MFMA ----------
// Block = one window (b, wi, wj): 512 threads = 8 waves = 4 heads x 2 row-halves.
// Wave owns 8 M-tiles (128 tokens) of its head. Chunk loop over s in 8 x 32.
__global__ __launch_bounds__(512) void win16_mfma(const float* __restrict__ x,
                                                  float* __restrict__ out) {
    const int blk = blockIdx.x;
    const int wj = blk & 15, wi = (blk >> 4) & 15, b = blk >> 8;
    const int tid  = threadIdx.x;
    const int lane = tid & 63;
    const int wave = tid >> 6;          // 0..7
    const int head = wave >> 1;
    const int half = wave & 1;          // token half: rows half*128 ..
    const int g = lane >> 4;            // lane group 0..3
    const int n = lane & 15;            // col-lane

    // LDS: q packed per token (hi0..3, lo0..3) for 16B frag reads;
    //      v packed per channel (token-contiguous) for B-frag gathers.
    __shared__ __align__(16) unsigned short qpack[4][256][8];  // 16 KB
    __shared__ unsigned short vh[4][4][260];                   // 8.1 KB (pad 260: kills 4-way bank conflict)
    __shared__ unsigned short vl[4][4][260];                   // 8.1 KB
    __shared__ __align__(16) float l_lds[4][256];              // 4 KB

    // ---- global -> LDS with bf16 hi/lo split. 32 planes x 256 tokens.
#pragma unroll
    for (int k = 0; k < 16; ++k) {
        const int f = k * 512 + tid;
        const int c = f >> 8;            // 0..31 within branch slice
        const int t = f & 255;
        const int gi = (wi * 16 + (t >> 4) + 248) & 255;   // shift (8,8): src = rolled-8 mod 256
        const int gj = (wj * 16 + (t & 15) + 248) & 255;
        const float val = x[((size_t)b * CIN + 32 + c) * PLANE + (size_t)gi * Ww + gj];
        const unsigned short hi = bfhi_u(val);
        const unsigned short lo = bfhi_u(val - bf2f(hi));
        const int h = (c >> 2) & 3, ch = c & 3;
        if (c < 16) { qpack[h][t][ch] = hi; qpack[h][t][4 + ch] = lo; }
        else        { vh[h][ch][t] = hi;    vl[h][ch][t] = lo; }
    }
    __syncthreads();

    const int tbase = half * 128;

    // ---- B-role Q fragments (t-tiles, fixed): lane holds token t = m*16+n.
    // K-slot placement lambda = 8g+j:  A:[s_hi0..3, s_lo0..3 | s_hi0..3, 0 | 0 | 0]
    //                                  B:[t_hi0..3, t_hi0..3 | t_lo0..3, 0 | 0 | 0]
    // => S = s_hi·t_hi + s_lo·t_hi + s_hi·t_lo.
    short8 BQ[8];
#pragma unroll
    for (int m = 0; m < 8; ++m) {
        const short8 q8 = *(const short8*)&qpack[head][tbase + m * 16 + n][0];
        short8 f = {0, 0, 0, 0, 0, 0, 0, 0};
#pragma unroll
        for (int j = 0; j < 4; ++j) {
            f[j]     = (g == 0) ? q8[j] : (g == 1) ? q8[4 + j] : (short)0;
            f[4 + j] = (g == 0) ? q8[j] : (short)0;
        }
        BQ[m] = f;
    }

    f32x4 O[8];
#pragma unroll
    for (int m = 0; m < 8; ++m) O[m] = (f32x4){0.f, 0.f, 0.f, 0.f};

    const f32x4 zero4 = (f32x4){0.f, 0.f, 0.f, 0.f};

    for (int c = 0; c < 8; ++c) {                 // s-chunks of 32
        // A-role Q fragments (s-tiles 2c, 2c+1)
        short8 AQ[2];
#pragma unroll
        for (int a = 0; a < 2; ++a) {
            const short8 q8 = *(const short8*)&qpack[head][c * 32 + a * 16 + n][0];
            short8 f = {0, 0, 0, 0, 0, 0, 0, 0};
#pragma unroll
            for (int j = 0; j < 4; ++j) {
                f[j]     = (g < 2) ? q8[j] : (short)0;       // hi (g0), hi (g1)
                f[4 + j] = (g == 0) ? q8[4 + j] : (short)0;  // lo (g0 only)
            }
            // g0: [hi,lo]  g1: [hi,0]  g2,g3: [0,0]
            AQ[a] = f;
        }

        // V B-fragments for this chunk; K-slot (g,j) <-> s-offset (j>>2)*16 + 4g + (j&3)
        short8 Vhf = {0, 0, 0, 0, 0, 0, 0, 0};
        short8 Vlf = {0, 0, 0, 0, 0, 0, 0, 0};
        if (n < 4) {
            const unsigned short* vhp = &vh[head][n][0];
            const unsigned short* vlp = &vl[head][n][0];
            const int s0 = c * 32 + 4 * g;
#pragma unroll
            for (int j = 0; j < 4; ++j) {
                Vhf[j]     = (short)vhp[s0 + j];
                Vhf[4 + j] = (short)vhp[s0 + 16 + j];
                Vlf[j]     = (short)vlp[s0 + j];
                Vlf[4 + j] = (short)vlp[s0 + 16 + j];
            }
        } else if (n == 4) {
#pragma unroll
            for (int j = 0; j < 8; ++j) Vhf[j] = (short)0x3F80;  // ones column -> row sums l
        }

        // QK^T: C[a][m] tile = S[s-tile 2c+a][t-tile m]; lane l, reg r:
        //   S[s = (2c+a)*16 + 4g + r][t = m*16 + n]
        f32x4 C[2][8];
#pragma unroll
        for (int a = 0; a < 2; ++a)
#pragma unroll
            for (int m = 0; m < 8; ++m)
                C[a][m] = __builtin_amdgcn_mfma_f32_16x16x32_bf16(AQ[a], BQ[m], zero4, 0, 0, 0);

        // exp + repack: by symmetry, C[a][m] holds exactly the PV A-fragment
        // values for M-tile m, slot j=(a,r): P[t=m*16+n][s offset a*16+4g+r].
#pragma unroll
        for (int m = 0; m < 8; ++m) {
            float pv[8];
#pragma unroll
            for (int j = 0; j < 8; ++j) pv[j] = __expf(C[j >> 2][m][j & 3]);
            short8 Pf, Plf;
#pragma unroll
            for (int j = 0; j < 8; ++j) {
                const unsigned short h = bfhi_u(pv[j]);
                Pf[j]  = (short)h;
                Plf[j] = (short)bfhi_u(pv[j] - bf2f(h));
            }
            O[m] = __builtin_amdgcn_mfma_f32_16x16x32_bf16(Pf,  Vhf, O[m], 0, 0, 0);
            O[m] = __builtin_amdgcn_mfma_f32_16x16x32_bf16(Pf,  Vlf, O[m], 0, 0, 0);
            O[m] = __builtin_amdgcn_mfma_f32_16x16x32_bf16(Plf, Vhf, O[m], 0, 0, 0);
        }
    }

    // ---- normalize: col 4 of O holds l[t]; publish 1/l via LDS (wave-local).
    if (n == 4) {
#pragma unroll
        for (int m = 0; m < 8; ++m)
#pragma unroll
            for (int r = 0; r < 4; ++r)
                l_lds[head][tbase + m * 16 + 4 * g + r] = __builtin_amdgcn_rcpf(O[m][r]);
    }
    // DS ops are wave-ordered; writes above land before reads below (no cross-wave sharing).
    if (n < 4) {
        float* op = out + ((size_t)b * COUT + 16 + head * 4 + n) * PLANE;
#pragma unroll
        for (int m = 0; m < 8; ++m) {
            const f32x4 inv4 = *(const f32x4*)&l_lds[head][tbase + m * 16 + 4 * g];
            const int gi  = (wi * 16 + half * 8 + m + 248) & 255;
            const int gj0 = (wj * 16 + 4 * g + 248) & 255;   // mult of 4, no mod-wrap inside float4
            f32x4 res;
            res[0] = O[m][0] * inv4[0];
            res[1] = O[m][1] * inv4[1];
            res[2] = O[m][2] * inv4[2];
            res[3] = O[m][3] * inv4[3];
            *(f32x4*)(op + (size_t)gi * Ww + gj0) = res;
        }
    }
}

extern "C" void kernel_launch(void* const* d_in, const int* in_sizes, int n_in,
                              void* d_out, int out_size, void* d_ws, size_t ws_size,
                              hipStream_t stream) {
    const float* x = (const float*)d_in[0];
    float* out = (float*)d_out;

    hipLaunchKernelGGL(win8_attn, dim3(16384), dim3(64), 0, stream, x, out);
    // b(4) x wi(16) x wj(16) = 1024 windows, 512 threads (8 waves)
    hipLaunchKernelGGL(win16_mfma, dim3(1024), dim3(512), 0, stream, x, out);
}

// Round 4
// 76.968 us; speedup vs baseline: 2.7027x; 1.2832x over previous
//
#include <hip/hip_runtime.h>
#include <math.h>

// Dual-branch shifted-window self-attention.
// Branch 0 (ch 0..31 in, ch 0..15 out): 8x8 windows, no shift  -> fp32 vector kernel.
// Branch 1 (ch 32..63 in, ch 16..31 out): 16x16 windows, shift (8,8) -> MFMA kernel.
//
// Key numerics: q is pre-scaled by ALPHA = sqrt(1/ln2) so S' = (q'·q'^T) = S/ln2
// and e^S = exp2(S') -> bare v_exp_f32, no mul, no max-subtraction (|S'| <= ~65,
// 2^65 well inside f32 range). P = bf16_rne(exp2(S')) used for BOTH numerator
// and the ones-column row-sum l, so the bf16 weight error self-normalizes.
// Q keeps a Dekker hi/lo split (S needs ~fp32 accuracy: exp amplifies absolute
// score error); V keeps a hi/lo split (cheap, per-chunk).
// Unnormalized P is SYMMETRIC, so the QK C-fragment of tile (s,t) is directly
// the PV A-fragment of tile (t,s): exp + cvt in-register, zero cross-lane.

typedef __attribute__((ext_vector_type(4))) float f32x4;
typedef __attribute__((ext_vector_type(8))) short short8;

static constexpr int Ww = 256;
static constexpr int CIN = 64;
static constexpr int COUT = 32;
static constexpr size_t PLANE = 65536; // 256*256
static constexpr float ALPHA = 1.2011224087864498f; // sqrt(1/ln2)

__device__ inline float fexp2(float x) {
#if __has_builtin(__builtin_amdgcn_exp2f)
    return __builtin_amdgcn_exp2f(x);
#else
    float r;
    asm("v_exp_f32 %0, %1" : "=v"(r) : "v"(x));   // v_exp_f32 IS 2^x
    return r;
#endif
}

// pack two f32 -> one u32 of 2x bf16 (RNE), single instruction on gfx950
__device__ inline unsigned cvt_pk_bf16(float lo, float hi) {
    unsigned r;
    asm("v_cvt_pk_bf16_f32 %0, %1, %2" : "=v"(r) : "v"(lo), "v"(hi));
    return r;
}

__device__ inline unsigned short bfhi_u(float x) {
    union { float f; unsigned u; } u; u.f = x;
    return (unsigned short)(u.u >> 16);            // truncation: fine for Dekker split
}
__device__ inline float bf2f(unsigned short h) {
    union { unsigned u; float f; } u; u.u = ((unsigned)h) << 16;
    return u.f;
}

// ---------------- branch 0: 8x8 windows, fp32 vector, exp2 + no-max ---------
__global__ __launch_bounds__(64) void win8_attn(const float* __restrict__ x,
                                                float* __restrict__ out) {
    int bid = blockIdx.x;
    const int wj   = bid & 31; bid >>= 5;
    const int wi   = bid & 31; bid >>= 5;
    const int head = bid & 3;  bid >>= 2;
    const int b    = bid;

    const int t  = threadIdx.x;
    const int gi = wi * 8 + (t >> 3);
    const int gj = wj * 8 + (t & 7);
    const size_t pix = (size_t)gi * Ww + gj;

    const float* xq = x + (size_t)b * CIN * PLANE + (size_t)(head * 4) * PLANE + pix;
    const float* xv = xq + 16 * PLANE;

    __shared__ float4 qs[64];
    __shared__ float4 vs[64];

    float4 q, v;
    q.x = xq[0] * ALPHA; q.y = xq[PLANE] * ALPHA;
    q.z = xq[2 * PLANE] * ALPHA; q.w = xq[3 * PLANE] * ALPHA;
    v.x = xv[0];         v.y = xv[PLANE];     v.z = xv[2 * PLANE]; v.w = xv[3 * PLANE];
    qs[t] = q;
    vs[t] = v;
    __syncthreads();

    // single fused pass: p = 2^(q'.q'_s), no max subtraction (range-safe)
    float l = 0.f;
    float4 acc = make_float4(0.f, 0.f, 0.f, 0.f);
#pragma unroll
    for (int s = 0; s < 64; ++s) {
        const float4 p = qs[s];
        const float d = q.x * p.x + q.y * p.y + q.z * p.z + q.w * p.w;
        const float e = fexp2(d);
        l += e;
        const float4 vv = vs[s];
        acc.x += e * vv.x; acc.y += e * vv.y;
        acc.z += e * vv.z; acc.w += e * vv.w;
    }
    const float inv = 1.0f / l;

    float* ob = out + (size_t)b * COUT * PLANE + (size_t)(head * 4) * PLANE + pix;
    ob[0]         = acc.x * inv;
    ob[PLANE]     = acc.y * inv;
    ob[2 * PLANE] = acc.z * inv;
    ob[3 * PLANE] = acc.w * inv;
}

// ---------------- branch 1: 16x16 windows via MFMA ----------
// Block = one window (b, wi, wj): 512 threads = 8 waves = 4 heads x 2 row-halves.
// Wave owns 8 M-tiles (128 tokens) of its head. Chunk loop over s in 8 x 32.
__global__ __launch_bounds__(512) void win16_mfma(const float* __restrict__ x,
                                                  float* __restrict__ out) {
    const int blk = blockIdx.x;
    const int wj = blk & 15, wi = (blk >> 4) & 15, b = blk >> 8;
    const int tid  = threadIdx.x;
    const int lane = tid & 63;
    const int wave = tid >> 6;          // 0..7
    const int head = wave >> 1;
    const int half = wave & 1;          // token half: rows half*128 ..
    const int g = lane >> 4;            // lane group 0..3
    const int n = lane & 15;            // col-lane

    __shared__ __align__(16) unsigned short qpack[4][256][8];  // 16 KB (hi0..3, lo0..3 per token)
    __shared__ unsigned short vh[4][4][260];                   // pad 260 kills 4-way conflict
    __shared__ unsigned short vl[4][4][260];
    __shared__ __align__(16) float l_lds[4][256];

    // ---- global -> LDS; q channels pre-scaled by ALPHA then Dekker-split.
#pragma unroll
    for (int k = 0; k < 16; ++k) {
        const int f = k * 512 + tid;
        const int c = f >> 8;            // 0..31 within branch slice
        const int t = f & 255;
        const int gi = (wi * 16 + (t >> 4) + 248) & 255;   // shift (8,8): src = rolled-8 mod 256
        const int gj = (wj * 16 + (t & 15) + 248) & 255;
        float val = x[((size_t)b * CIN + 32 + c) * PLANE + (size_t)gi * Ww + gj];
        if (c < 16) val *= ALPHA;
        const unsigned short hi = bfhi_u(val);
        const unsigned short lo = bfhi_u(val - bf2f(hi));
        const int h = (c >> 2) & 3, ch = c & 3;
        if (c < 16) { qpack[h][t][ch] = hi; qpack[h][t][4 + ch] = lo; }
        else        { vh[h][ch][t] = hi;    vl[h][ch][t] = lo; }
    }
    __syncthreads();

    const int tbase = half * 128;

    // u64 masks for fragment construction (replaces per-element cndmask)
    const unsigned long long m0  = (g == 0) ? ~0ull : 0ull;
    const unsigned long long m1  = (g == 1) ? ~0ull : 0ull;
    const unsigned long long m01 = (g <  2) ? ~0ull : 0ull;

    // ---- B-role Q fragments (t-tiles, fixed): lane holds token t = m*16+n.
    // K-slot placement: A:[s_hi(g0) s_hi(g1) 0 0 | s_lo(g0) 0 0 0]
    //                   B:[t_hi(g0) t_lo(g1) 0 0 | t_hi(g0) 0 0 0]
    // => S = s_hi·t_hi + s_hi·t_lo + s_lo·t_hi.
    short8 BQ[8];
#pragma unroll
    for (int m = 0; m < 8; ++m) {
        union { short8 v; unsigned long long q[2]; } u, f;
        u.v = *(const short8*)&qpack[head][tbase + m * 16 + n][0];
        f.q[0] = (u.q[0] & m0) | (u.q[1] & m1);
        f.q[1] = u.q[0] & m0;
        BQ[m] = f.v;
    }

    f32x4 O[8];
#pragma unroll
    for (int m = 0; m < 8; ++m) O[m] = (f32x4){0.f, 0.f, 0.f, 0.f};

    const f32x4 zero4 = (f32x4){0.f, 0.f, 0.f, 0.f};

    for (int c = 0; c < 8; ++c) {                 // s-chunks of 32
        // A-role Q fragments (s-tiles 2c, 2c+1)
        short8 AQ[2];
#pragma unroll
        for (int a = 0; a < 2; ++a) {
            union { short8 v; unsigned long long q[2]; } u, f;
            u.v = *(const short8*)&qpack[head][c * 32 + a * 16 + n][0];
            f.q[0] = u.q[0] & m01;
            f.q[1] = u.q[1] & m0;
            AQ[a] = f.v;
        }

        // V B-fragments; K-slot (g,j) <-> s-offset (j>>2)*16 + 4g + (j&3)
        short8 Vhf = {0, 0, 0, 0, 0, 0, 0, 0};
        short8 Vlf = {0, 0, 0, 0, 0, 0, 0, 0};
        if (n < 4) {
            const unsigned short* vhp = &vh[head][n][0];
            const unsigned short* vlp = &vl[head][n][0];
            const int s0 = c * 32 + 4 * g;
#pragma unroll
            for (int j = 0; j < 4; ++j) {
                Vhf[j]     = (short)vhp[s0 + j];
                Vhf[4 + j] = (short)vhp[s0 + 16 + j];
                Vlf[j]     = (short)vlp[s0 + j];
                Vlf[4 + j] = (short)vlp[s0 + 16 + j];
            }
        } else if (n == 4) {
#pragma unroll
            for (int j = 0; j < 8; ++j) Vhf[j] = (short)0x3F80;  // ones column -> row sums l
        }

        // per m: QK (2 MFMA) -> exp2 -> bf16 pack (cvt_pk) -> PV (2 MFMA).
        // By symmetry C[a][m] holds exactly the PV A-fragment values for
        // M-tile m, K-slot j=(a,r): P[t=m*16+n][s offset a*16+4g+r].
#pragma unroll
        for (int m = 0; m < 8; ++m) {
            const f32x4 c0 = __builtin_amdgcn_mfma_f32_16x16x32_bf16(AQ[0], BQ[m], zero4, 0, 0, 0);
            const f32x4 c1 = __builtin_amdgcn_mfma_f32_16x16x32_bf16(AQ[1], BQ[m], zero4, 0, 0, 0);
            union { unsigned u[4]; short8 s; } pk;
#pragma unroll
            for (int k = 0; k < 4; ++k) {
                const float pa = fexp2(k < 2 ? c0[2 * k] : c1[2 * k - 4]);
                const float pb = fexp2(k < 2 ? c0[2 * k + 1] : c1[2 * k - 3]);
                pk.u[k] = cvt_pk_bf16(pa, pb);
            }
            O[m] = __builtin_amdgcn_mfma_f32_16x16x32_bf16(pk.s, Vhf, O[m], 0, 0, 0);
            O[m] = __builtin_amdgcn_mfma_f32_16x16x32_bf16(pk.s, Vlf, O[m], 0, 0, 0);
        }
    }

    // ---- normalize: col 4 of O holds l[t]; publish 1/l via LDS (wave-local).
    if (n == 4) {
#pragma unroll
        for (int m = 0; m < 8; ++m)
#pragma unroll
            for (int r = 0; r < 4; ++r)
                l_lds[head][tbase + m * 16 + 4 * g + r] = __builtin_amdgcn_rcpf(O[m][r]);
    }
    // DS ops are wave-ordered; writes above land before reads below (no cross-wave sharing).
    if (n < 4) {
        float* op = out + ((size_t)b * COUT + 16 + head * 4 + n) * PLANE;
#pragma unroll
        for (int m = 0; m < 8; ++m) {
            const f32x4 inv4 = *(const f32x4*)&l_lds[head][tbase + m * 16 + 4 * g];
            const int gi  = (wi * 16 + half * 8 + m + 248) & 255;
            const int gj0 = (wj * 16 + 4 * g + 248) & 255;   // mult of 4, no mod-wrap inside float4
            f32x4 res;
            res[0] = O[m][0] * inv4[0];
            res[1] = O[m][1] * inv4[1];
            res[2] = O[m][2] * inv4[2];
            res[3] = O[m][3] * inv4[3];
            *(f32x4*)(op + (size_t)gi * Ww + gj0) = res;
        }
    }
}

extern "C" void kernel_launch(void* const* d_in, const int* in_sizes, int n_in,
                              void* d_out, int out_size, void* d_ws, size_t ws_size,
                              hipStream_t stream) {
    const float* x = (const float*)d_in[0];
    float* out = (float*)d_out;

    hipLaunchKernelGGL(win8_attn, dim3(16384), dim3(64), 0, stream, x, out);
    // b(4) x wi(16) x wj(16) = 1024 windows, 512 threads (8 waves)
    hipLaunchKernelGGL(win16_mfma, dim3(1024), dim3(512), 0, stream, x, out);
}

// Round 6
// 74.816 us; speedup vs baseline: 2.7804x; 1.0288x over previous
//
#include <hip/hip_runtime.h>
#include <math.h>

// Dual-branch shifted-window self-attention.
// Branch 0 (ch 0..31 in, ch 0..15 out): 8x8 windows, no shift -> fp32 vector kernel
//   (round-4 passing version, reverted as bisect control).
// Branch 1 (ch 32..63 in, ch 16..31 out): 16x16 windows, shift (8,8) -> MFMA kernel
//   (round-5 version under test: V as single bf16-RNE, 3 MFMA per m-tile).

typedef __attribute__((ext_vector_type(4))) float f32x4;
typedef __attribute__((ext_vector_type(8))) short short8;
typedef __attribute__((ext_vector_type(4))) unsigned short ushort4v;

static constexpr int Ww = 256;
static constexpr int CIN = 64;
static constexpr int COUT = 32;
static constexpr size_t PLANE = 65536; // 256*256
static constexpr float ALPHA = 1.2011224087864498f; // sqrt(1/ln2)

__device__ inline float fexp2(float x) {
#if __has_builtin(__builtin_amdgcn_exp2f)
    return __builtin_amdgcn_exp2f(x);
#else
    float r;
    asm("v_exp_f32 %0, %1" : "=v"(r) : "v"(x));   // v_exp_f32 IS 2^x
    return r;
#endif
}

// pack two f32 -> one u32 of 2x bf16 (RNE), single instruction on gfx950
__device__ inline unsigned cvt_pk_bf16(float lo, float hi) {
    unsigned r;
    asm("v_cvt_pk_bf16_f32 %0, %1, %2" : "=v"(r) : "v"(lo), "v"(hi));
    return r;
}

__device__ inline unsigned short bfhi_u(float x) {   // truncation (Dekker hi)
    union { float f; unsigned u; } u; u.f = x;
    return (unsigned short)(u.u >> 16);
}
__device__ inline float bf2f(unsigned short h) {
    union { unsigned u; float f; } u; u.u = ((unsigned)h) << 16;
    return u.f;
}
__device__ inline unsigned short bf_rne(float x) {   // round-nearest-even bf16
    union { float f; unsigned u; } u; u.f = x;
    return (unsigned short)((u.u + 0x7FFFu + ((u.u >> 16) & 1u)) >> 16);
}

// ------------- branch 0: 8x8 windows, fp32 vector (round-4 passing) ---------
__global__ __launch_bounds__(64) void win8_attn(const float* __restrict__ x,
                                                float* __restrict__ out) {
    int bid = blockIdx.x;
    const int wj   = bid & 31; bid >>= 5;
    const int wi   = bid & 31; bid >>= 5;
    const int head = bid & 3;  bid >>= 2;
    const int b    = bid;

    const int t  = threadIdx.x;
    const int gi = wi * 8 + (t >> 3);
    const int gj = wj * 8 + (t & 7);
    const size_t pix = (size_t)gi * Ww + gj;

    const float* xq = x + (size_t)b * CIN * PLANE + (size_t)(head * 4) * PLANE + pix;
    const float* xv = xq + 16 * PLANE;

    __shared__ float4 qs[64];
    __shared__ float4 vs[64];

    float4 q, v;
    q.x = xq[0] * ALPHA; q.y = xq[PLANE] * ALPHA;
    q.z = xq[2 * PLANE] * ALPHA; q.w = xq[3 * PLANE] * ALPHA;
    v.x = xv[0];         v.y = xv[PLANE];     v.z = xv[2 * PLANE]; v.w = xv[3 * PLANE];
    qs[t] = q;
    vs[t] = v;
    __syncthreads();

    float l = 0.f;
    float4 acc = make_float4(0.f, 0.f, 0.f, 0.f);
#pragma unroll
    for (int s = 0; s < 64; ++s) {
        const float4 p = qs[s];
        const float d = q.x * p.x + q.y * p.y + q.z * p.z + q.w * p.w;
        const float e = fexp2(d);
        l += e;
        const float4 vv = vs[s];
        acc.x += e * vv.x; acc.y += e * vv.y;
        acc.z += e * vv.z; acc.w += e * vv.w;
    }
    const float inv = 1.0f / l;

    float* ob = out + (size_t)b * COUT * PLANE + (size_t)(head * 4) * PLANE + pix;
    ob[0]         = acc.x * inv;
    ob[PLANE]     = acc.y * inv;
    ob[2 * PLANE] = acc.z * inv;
    ob[3 * PLANE] = acc.w * inv;
}

// =================== branch 1: 16x16 windows, shift (8,8) ===================
// Block = one window: 512 thr = 8 waves = 4 heads x 2 row-halves; wave owns
// 8 M-tiles (128 tokens). s-chunk loop 8 x 32.
__global__ __launch_bounds__(512) void win16_mfma(const float* __restrict__ x,
                                                  float* __restrict__ out) {
    const int blk = blockIdx.x;
    const int wj = blk & 15, wi = (blk >> 4) & 15, b = blk >> 8;
    const int tid  = threadIdx.x;
    const int lane = tid & 63;
    const int wave = tid >> 6;
    const int head = wave >> 1;
    const int half = wave & 1;
    const int g = lane >> 4;
    const int n = lane & 15;

    __shared__ __align__(16) unsigned short qpack[4][256][8];  // 16 KB (hi0..3, lo0..3)
    __shared__ __align__(8)  unsigned short vh[4][4][260];     // 8.1 KB (pad kills conflicts)
    __shared__ __align__(16) float l_lds[4][256];              // 4 KB

    // ---- global -> LDS; q * ALPHA then Dekker split; v bf16-RNE.
#pragma unroll
    for (int k = 0; k < 16; ++k) {
        const int f = k * 512 + tid;
        const int c = f >> 8;            // 0..31
        const int t = f & 255;
        const int gi = (wi * 16 + (t >> 4) + 248) & 255;   // shift: src = rolled-8 mod 256
        const int gj = (wj * 16 + (t & 15) + 248) & 255;
        float val = x[((size_t)b * CIN + 32 + c) * PLANE + (size_t)gi * Ww + gj];
        const int h = (c >> 2) & 3, ch = c & 3;
        if (c < 16) {
            val *= ALPHA;
            const unsigned short hi = bfhi_u(val);
            qpack[h][t][ch]     = hi;
            qpack[h][t][4 + ch] = bfhi_u(val - bf2f(hi));
        } else {
            vh[h][ch][t] = bf_rne(val);
        }
    }
    __syncthreads();

    const int tbase = half * 128;

    const unsigned long long m0  = (g == 0) ? ~0ull : 0ull;
    const unsigned long long m1  = (g == 1) ? ~0ull : 0ull;
    const unsigned long long m01 = (g <  2) ? ~0ull : 0ull;

    // K-slot placement: A:[s_hi(g0) s_hi(g1) 0 0 | s_lo(g0) 0 0 0]
    //                   B:[t_hi(g0) t_lo(g1) 0 0 | t_hi(g0) 0 0 0]
    // => S = s_hi·t_hi + s_hi·t_lo + s_lo·t_hi.
    short8 BQ[8];
#pragma unroll
    for (int m = 0; m < 8; ++m) {
        union { short8 v; unsigned long long q[2]; } u, f;
        u.v = *(const short8*)&qpack[head][tbase + m * 16 + n][0];
        f.q[0] = (u.q[0] & m0) | (u.q[1] & m1);
        f.q[1] = u.q[0] & m0;
        BQ[m] = f.v;
    }

    f32x4 O[8];
#pragma unroll
    for (int m = 0; m < 8; ++m) O[m] = (f32x4){0.f, 0.f, 0.f, 0.f};
    const f32x4 zero4 = (f32x4){0.f, 0.f, 0.f, 0.f};

    for (int c = 0; c < 8; ++c) {                 // s-chunks of 32
        short8 AQ[2];
#pragma unroll
        for (int a = 0; a < 2; ++a) {
            union { short8 v; unsigned long long q[2]; } u, f;
            u.v = *(const short8*)&qpack[head][c * 32 + a * 16 + n][0];
            f.q[0] = u.q[0] & m01;
            f.q[1] = u.q[1] & m0;
            AQ[a] = f.v;
        }

        // V B-fragment; K-slot (g,j) <-> s-offset (j>>2)*16 + 4g + (j&3)
        short8 Vhf = {0, 0, 0, 0, 0, 0, 0, 0};
        if (n < 4) {
            const int s0 = c * 32 + 4 * g;
            const ushort4v a = *(const ushort4v*)&vh[head][n][s0];
            const ushort4v bvec = *(const ushort4v*)&vh[head][n][s0 + 16];
#pragma unroll
            for (int j = 0; j < 4; ++j) { Vhf[j] = (short)a[j]; Vhf[4 + j] = (short)bvec[j]; }
        } else if (n == 4) {
#pragma unroll
            for (int j = 0; j < 8; ++j) Vhf[j] = (short)0x3F80;  // ones -> row sums l
        }

        // per m: QK (2 MFMA) -> exp2 -> cvt_pk -> PV (1 MFMA).
#pragma unroll
        for (int m = 0; m < 8; ++m) {
            const f32x4 c0 = __builtin_amdgcn_mfma_f32_16x16x32_bf16(AQ[0], BQ[m], zero4, 0, 0, 0);
            const f32x4 c1 = __builtin_amdgcn_mfma_f32_16x16x32_bf16(AQ[1], BQ[m], zero4, 0, 0, 0);
            union { unsigned u[4]; short8 s; } pk;
            pk.u[0] = cvt_pk_bf16(fexp2(c0[0]), fexp2(c0[1]));
            pk.u[1] = cvt_pk_bf16(fexp2(c0[2]), fexp2(c0[3]));
            pk.u[2] = cvt_pk_bf16(fexp2(c1[0]), fexp2(c1[1]));
            pk.u[3] = cvt_pk_bf16(fexp2(c1[2]), fexp2(c1[3]));
            O[m] = __builtin_amdgcn_mfma_f32_16x16x32_bf16(pk.s, Vhf, O[m], 0, 0, 0);
        }
    }

    // ---- normalize: col 4 holds l[t]; publish 1/l via LDS (wave-local; DS wave-ordered).
    if (n == 4) {
#pragma unroll
        for (int m = 0; m < 8; ++m)
#pragma unroll
            for (int r = 0; r < 4; ++r)
                l_lds[head][tbase + m * 16 + 4 * g + r] = __builtin_amdgcn_rcpf(O[m][r]);
    }
    if (n < 4) {
        float* op = out + ((size_t)b * COUT + 16 + head * 4 + n) * PLANE;
#pragma unroll
        for (int m = 0; m < 8; ++m) {
            const f32x4 inv4 = *(const f32x4*)&l_lds[head][tbase + m * 16 + 4 * g];
            const int gi  = (wi * 16 + half * 8 + m + 248) & 255;
            const int gj0 = (wj * 16 + 4 * g + 248) & 255;
            f32x4 res;
            res[0] = O[m][0] * inv4[0];
            res[1] = O[m][1] * inv4[1];
            res[2] = O[m][2] * inv4[2];
            res[3] = O[m][3] * inv4[3];
            *(f32x4*)(op + (size_t)gi * Ww + gj0) = res;
        }
    }
}

extern "C" void kernel_launch(void* const* d_in, const int* in_sizes, int n_in,
                              void* d_out, int out_size, void* d_ws, size_t ws_size,
                              hipStream_t stream) {
    const float* x = (const float*)d_in[0];
    float* out = (float*)d_out;

    // branch 0: 4 batches x 4 heads x 32 x 32 windows, 64 thr (1 wave)
    hipLaunchKernelGGL(win8_attn, dim3(16384), dim3(64), 0, stream, x, out);
    // branch 1: 4 x 16 x 16 windows, 512 thr (8 waves = 4 heads x 2 halves)
    hipLaunchKernelGGL(win16_mfma, dim3(1024), dim3(512), 0, stream, x, out);
}

// Round 9
// 59.529 us; speedup vs baseline: 3.4945x; 1.2568x over previous
//
#include <hip/hip_runtime.h>
#include <math.h>

// Dual-branch shifted-window self-attention — FUSED single kernel.
// Blocks 0..1023:  branch 1 (16x16 windows, shift (8,8), ch 32..63 -> out 16..31),
//                  MFMA body verbatim from the round-6 PASSING kernel.
// Blocks 1024..3071: branch 0 (8x8 windows, no shift, ch 0..31 -> out 0..15),
//                  fp32 vector body verbatim from the round-6 PASSING kernel,
//                  run as 8 independent waves per block (wave-private LDS
//                  slices; no __syncthreads needed: DS pipe is in-order per
//                  wave, so a wave's ds_reads see its own earlier ds_writes).
// Fusion rationale: win16 alone leaves ~46% of VALU issue slots idle
// (VALUBusy 54%) while win8 alone is ~100% VALU-bound for ~27us; co-resident
// blocks overlap the two.  win16 blocks first (long pole), win8 backfills.
//
// Numerics (verified rounds 4/6): q pre-scaled by sqrt(1/ln2) so e^S =
// exp2(q'.q'^T) — bare v_exp_f32, no max subtraction. P = bf16_rne(exp2),
// used for BOTH numerator and ones-column row-sum l (self-normalizing).
// Q Dekker hi/lo; V bf16-RNE. Unnormalized P is symmetric: QK C-fragment of
// tile (s,t) IS the PV A-fragment of tile (t,s) under the shared K-slot
// placement -> exp + cvt in-register, no cross-lane traffic.

typedef __attribute__((ext_vector_type(4))) float f32x4;
typedef __attribute__((ext_vector_type(8))) short short8;
typedef __attribute__((ext_vector_type(4))) unsigned short ushort4v;

static constexpr int Ww = 256;
static constexpr int CIN = 64;
static constexpr int COUT = 32;
static constexpr size_t PLANE = 65536; // 256*256
static constexpr float ALPHA = 1.2011224087864498f; // sqrt(1/ln2)

__device__ inline float fexp2(float x) {
#if __has_builtin(__builtin_amdgcn_exp2f)
    return __builtin_amdgcn_exp2f(x);
#else
    float r;
    asm("v_exp_f32 %0, %1" : "=v"(r) : "v"(x));   // v_exp_f32 IS 2^x
    return r;
#endif
}

__device__ inline unsigned cvt_pk_bf16(float lo, float hi) {
    unsigned r;
    asm("v_cvt_pk_bf16_f32 %0, %1, %2" : "=v"(r) : "v"(lo), "v"(hi));
    return r;
}

__device__ inline unsigned short bfhi_u(float x) {   // truncation (Dekker hi)
    union { float f; unsigned u; } u; u.f = x;
    return (unsigned short)(u.u >> 16);
}
__device__ inline float bf2f(unsigned short h) {
    union { unsigned u; float f; } u; u.u = ((unsigned)h) << 16;
    return u.f;
}
__device__ inline unsigned short bf_rne(float x) {   // round-nearest-even bf16
    union { float f; unsigned u; } u; u.f = x;
    return (unsigned short)((u.u + 0x7FFFu + ((u.u >> 16) & 1u)) >> 16);
}

struct Smem16 {                                   // 28800 B (win16 path)
    unsigned short qpack[4][256][8];              // 16384
    unsigned short vh[4][4][260];                 // 8320 (pad kills conflicts)
    float l_lds[4][256];                          // 4096 (offset 24704, 16-aligned)
};
struct Smem8 {                                    // 16384 B (win8 path)
    float4 qs[8][64];
    float4 vs[8][64];
};
union SmemU { Smem16 a; Smem8 b; };

__global__ __launch_bounds__(512) void fused_attn(const float* __restrict__ x,
                                                  float* __restrict__ out) {
    __shared__ __align__(16) SmemU smem;

    const int tid  = threadIdx.x;
    const int lane = tid & 63;
    const int wave = tid >> 6;

    if (blockIdx.x < 1024) {
        // ================= branch 1: 16x16, shift (8,8), MFMA ================
        const int blk = blockIdx.x;
        const int wj = blk & 15, wi = (blk >> 4) & 15, b = blk >> 8;
        const int head = wave >> 1;
        const int half = wave & 1;
        const int g = lane >> 4;
        const int n = lane & 15;

        // ---- global -> LDS; q * ALPHA then Dekker split; v bf16-RNE.
#pragma unroll
        for (int k = 0; k < 16; ++k) {
            const int f = k * 512 + tid;
            const int c = f >> 8;            // 0..31
            const int t = f & 255;
            const int gi = (wi * 16 + (t >> 4) + 248) & 255;   // src = rolled-8 mod 256
            const int gj = (wj * 16 + (t & 15) + 248) & 255;
            float val = x[((size_t)b * CIN + 32 + c) * PLANE + (size_t)gi * Ww + gj];
            const int h = (c >> 2) & 3, ch = c & 3;
            if (c < 16) {
                val *= ALPHA;
                const unsigned short hi = bfhi_u(val);
                smem.a.qpack[h][t][ch]     = hi;
                smem.a.qpack[h][t][4 + ch] = bfhi_u(val - bf2f(hi));
            } else {
                smem.a.vh[h][ch][t] = bf_rne(val);
            }
        }
        __syncthreads();

        const int tbase = half * 128;

        const unsigned long long m0  = (g == 0) ? ~0ull : 0ull;
        const unsigned long long m1  = (g == 1) ? ~0ull : 0ull;
        const unsigned long long m01 = (g <  2) ? ~0ull : 0ull;

        // K-slot placement: A:[s_hi(g0) s_hi(g1) 0 0 | s_lo(g0) 0 0 0]
        //                   B:[t_hi(g0) t_lo(g1) 0 0 | t_hi(g0) 0 0 0]
        short8 BQ[8];
#pragma unroll
        for (int m = 0; m < 8; ++m) {
            union { short8 v; unsigned long long q[2]; } u, f;
            u.v = *(const short8*)&smem.a.qpack[head][tbase + m * 16 + n][0];
            f.q[0] = (u.q[0] & m0) | (u.q[1] & m1);
            f.q[1] = u.q[0] & m0;
            BQ[m] = f.v;
        }

        f32x4 O[8];
#pragma unroll
        for (int m = 0; m < 8; ++m) O[m] = (f32x4){0.f, 0.f, 0.f, 0.f};
        const f32x4 zero4 = (f32x4){0.f, 0.f, 0.f, 0.f};

        for (int c = 0; c < 8; ++c) {                 // s-chunks of 32
            short8 AQ[2];
#pragma unroll
            for (int a = 0; a < 2; ++a) {
                union { short8 v; unsigned long long q[2]; } u, f;
                u.v = *(const short8*)&smem.a.qpack[head][c * 32 + a * 16 + n][0];
                f.q[0] = u.q[0] & m01;
                f.q[1] = u.q[1] & m0;
                AQ[a] = f.v;
            }

            short8 Vhf = {0, 0, 0, 0, 0, 0, 0, 0};
            if (n < 4) {
                const int s0 = c * 32 + 4 * g;
                const ushort4v va = *(const ushort4v*)&smem.a.vh[head][n][s0];
                const ushort4v vb = *(const ushort4v*)&smem.a.vh[head][n][s0 + 16];
#pragma unroll
                for (int j = 0; j < 4; ++j) { Vhf[j] = (short)va[j]; Vhf[4 + j] = (short)vb[j]; }
            } else if (n == 4) {
#pragma unroll
                for (int j = 0; j < 8; ++j) Vhf[j] = (short)0x3F80;  // ones -> l
            }

#pragma unroll
            for (int m = 0; m < 8; ++m) {
                const f32x4 c0 = __builtin_amdgcn_mfma_f32_16x16x32_bf16(AQ[0], BQ[m], zero4, 0, 0, 0);
                const f32x4 c1 = __builtin_amdgcn_mfma_f32_16x16x32_bf16(AQ[1], BQ[m], zero4, 0, 0, 0);
                union { unsigned u[4]; short8 s; } pk;
                pk.u[0] = cvt_pk_bf16(fexp2(c0[0]), fexp2(c0[1]));
                pk.u[1] = cvt_pk_bf16(fexp2(c0[2]), fexp2(c0[3]));
                pk.u[2] = cvt_pk_bf16(fexp2(c1[0]), fexp2(c1[1]));
                pk.u[3] = cvt_pk_bf16(fexp2(c1[2]), fexp2(c1[3]));
                O[m] = __builtin_amdgcn_mfma_f32_16x16x32_bf16(pk.s, Vhf, O[m], 0, 0, 0);
            }
        }

        if (n == 4) {
#pragma unroll
            for (int m = 0; m < 8; ++m)
#pragma unroll
                for (int r = 0; r < 4; ++r)
                    smem.a.l_lds[head][tbase + m * 16 + 4 * g + r] = __builtin_amdgcn_rcpf(O[m][r]);
        }
        if (n < 4) {
            float* op = out + ((size_t)b * COUT + 16 + head * 4 + n) * PLANE;
#pragma unroll
            for (int m = 0; m < 8; ++m) {
                const f32x4 inv4 = *(const f32x4*)&smem.a.l_lds[head][tbase + m * 16 + 4 * g];
                const int gi  = (wi * 16 + half * 8 + m + 248) & 255;
                const int gj0 = (wj * 16 + 4 * g + 248) & 255;
                f32x4 res;
                res[0] = O[m][0] * inv4[0];
                res[1] = O[m][1] * inv4[1];
                res[2] = O[m][2] * inv4[2];
                res[3] = O[m][3] * inv4[3];
                *(f32x4*)(op + (size_t)gi * Ww + gj0) = res;
            }
        }
    } else {
        // ============ branch 0: 8x8, no shift, fp32 vector (per-wave) ========
        int bid = (blockIdx.x - 1024) * 8 + wave;   // 0..16383
        const int wj   = bid & 31; bid >>= 5;
        const int wi   = bid & 31; bid >>= 5;
        const int head = bid & 3;  bid >>= 2;
        const int b    = bid;

        const int t  = lane;
        const int gi = wi * 8 + (t >> 3);
        const int gj = wj * 8 + (t & 7);
        const size_t pix = (size_t)gi * Ww + gj;

        const float* xq = x + (size_t)b * CIN * PLANE + (size_t)(head * 4) * PLANE + pix;
        const float* xv = xq + 16 * PLANE;

        float4* qs = smem.b.qs[wave];
        float4* vs = smem.b.vs[wave];

        float4 q, v;
        q.x = xq[0] * ALPHA; q.y = xq[PLANE] * ALPHA;
        q.z = xq[2 * PLANE] * ALPHA; q.w = xq[3 * PLANE] * ALPHA;
        v.x = xv[0];         v.y = xv[PLANE];     v.z = xv[2 * PLANE]; v.w = xv[3 * PLANE];
        qs[t] = q;
        vs[t] = v;
        // no barrier: qs/vs slices are wave-private; DS pipe is in-order per wave.

        float l = 0.f;
        float4 acc = make_float4(0.f, 0.f, 0.f, 0.f);
#pragma unroll
        for (int s = 0; s < 64; ++s) {
            const float4 p = qs[s];
            const float d = q.x * p.x + q.y * p.y + q.z * p.z + q.w * p.w;
            const float e = fexp2(d);
            l += e;
            const float4 vv = vs[s];
            acc.x += e * vv.x; acc.y += e * vv.y;
            acc.z += e * vv.z; acc.w += e * vv.w;
        }
        const float inv = 1.0f / l;

        float* ob = out + (size_t)b * COUT * PLANE + (size_t)(head * 4) * PLANE + pix;
        ob[0]         = acc.x * inv;
        ob[PLANE]     = acc.y * inv;
        ob[2 * PLANE] = acc.z * inv;
        ob[3 * PLANE] = acc.w * inv;
    }
}

extern "C" void kernel_launch(void* const* d_in, const int* in_sizes, int n_in,
                              void* d_out, int out_size, void* d_ws, size_t ws_size,
                              hipStream_t stream) {
    const float* x = (const float*)d_in[0];
    float* out = (float*)d_out;

    // blocks 0..1023: win16 (4 x 16 x 16 windows); blocks 1024..3071: win8
    // (16384 window-heads / 8 waves per block).  Long-running win16 first.
    hipLaunchKernelGGL(fused_attn, dim3(3072), dim3(512), 0, stream, x, out);
}